// Round 4
// baseline (377.348 us; speedup 1.0000x reference)
//
#include <hip/hip_runtime.h>
#include <math.h>

#define B 128
#define T 1024
#define H 256
#define L 16
#define INV_TEMP (1.0f/0.07f)
#define NEG_INF -1e30f

// ws layout (only seg<nseg regions are ever written/read -> no memset):
//   ws_pp   : float[B][4][L][H]   per-seg prototype partial sums   8 MB
//   ws_cntp : int[B][4][L]        per-seg label counts             32 KB

// ---------------------------------------------------------------------------
// Kernel 1: prototype partial sums. grid = B * 2 chunks * 4 segs = 1024 blocks.
// v4: LDS float atomics (ds_add_f32, fire-and-forget) replace the serialized
// read-modify-write chains of v3 (compiler had to serialize 4 aliasing RMWs
// per unroll group -> ~120cy x 4 dependent LDS round-trips per 4 tokens).
// Single block-shared accumulator in deinterleaved layout acc[q][l][m]
// (feature coord = m*4+q): every ds_add_f32 hits bank (lane&31) -> 2 lanes
// per bank = conflict-free. Global loads upgraded float2 -> float4 (1KB/wave,
// wave covers 2 tokens per load step). Loop body = 4 independent loads +
// 16 independent atomics; no dependency chains at all.
__global__ __launch_bounds__(256) void proto_kernel(
    const float* __restrict__ feat, const int* __restrict__ dlen,
    const int* __restrict__ labels, float* __restrict__ ws_pp,
    int* __restrict__ ws_cntp, float* __restrict__ out) {
  __shared__ float acc[4][L][32];   // 8 KB, deinterleaved (see above)
  __shared__ int labs[256];
  __shared__ int cnt[L];

  const int bx = blockIdx.x;
  if (bx == 0 && threadIdx.x == 0) out[0] = 0.f;   // replaces memset dispatch

  const int b = bx >> 3;
  const int chunk = (bx >> 2) & 1;
  const int seg = bx & 3;
  const int tid = threadIdx.x;

  const int len = dlen[b];
  if (seg * 256 >= len) return;   // fully invalid segment: nothing published

  for (int i = tid; i < 4 * L * 32 / 4; i += 256)   // 512 float4 -> 2 iters
    ((float4*)acc)[i] = make_float4(0.f, 0.f, 0.f, 0.f);
  labs[tid] = labels[(size_t)b * T + seg * 256 + tid];
  if (tid < L) cnt[tid] = 0;
  __syncthreads();

  if (chunk == 0 && (seg * 256 + tid) < len) atomicAdd(&cnt[labs[tid]], 1);

  const int w = tid >> 6;          // wave: tokens [w*64, w*64+64)
  const int lane = tid & 63;
  const int half = lane >> 5;      // which token of the pair this lane covers
  const int m = lane & 31;         // float4 index within the 128-float chunk

  int nt = len - seg * 256 - w * 64;   // tokens this wave processes
  if (nt > 64) nt = 64;
  // float4 view of this wave's first token row (chunk half of H)
  const float4* fb = (const float4*)(feat +
      ((size_t)b * T + seg * 256 + w * 64) * H + chunk * 128);
  // token tr (relative) chunk element m lives at fb[tr*64 + m]

  if (nt == 64) {                  // fast path: all 32 pairs valid
    for (int j = 0; j < 32; j += 4) {
      const float4 f0 = fb[(size_t)(2 * j + 0 + half) * 64 + m];
      const float4 f1 = fb[(size_t)(2 * j + 2 + half) * 64 + m];
      const float4 f2 = fb[(size_t)(2 * j + 4 + half) * 64 + m];
      const float4 f3 = fb[(size_t)(2 * j + 6 + half) * 64 + m];
      const int l0 = labs[w * 64 + 2 * j + 0 + half];
      const int l1 = labs[w * 64 + 2 * j + 2 + half];
      const int l2 = labs[w * 64 + 2 * j + 4 + half];
      const int l3 = labs[w * 64 + 2 * j + 6 + half];
      atomicAdd(&acc[0][l0][m], f0.x); atomicAdd(&acc[1][l0][m], f0.y);
      atomicAdd(&acc[2][l0][m], f0.z); atomicAdd(&acc[3][l0][m], f0.w);
      atomicAdd(&acc[0][l1][m], f1.x); atomicAdd(&acc[1][l1][m], f1.y);
      atomicAdd(&acc[2][l1][m], f1.z); atomicAdd(&acc[3][l1][m], f1.w);
      atomicAdd(&acc[0][l2][m], f2.x); atomicAdd(&acc[1][l2][m], f2.y);
      atomicAdd(&acc[2][l2][m], f2.z); atomicAdd(&acc[3][l2][m], f2.w);
      atomicAdd(&acc[0][l3][m], f3.x); atomicAdd(&acc[1][l3][m], f3.y);
      atomicAdd(&acc[2][l3][m], f3.z); atomicAdd(&acc[3][l3][m], f3.w);
    }
  } else {                         // tail segment: per-pair bound check
    for (int j = 0; j < 32; ++j) {
      const int tr = 2 * j + half;
      if (tr >= nt) break;         // exec-mask divergence handles odd nt
      const float4 f = fb[(size_t)tr * 64 + m];
      const int l = labs[w * 64 + tr];
      atomicAdd(&acc[0][l][m], f.x); atomicAdd(&acc[1][l][m], f.y);
      atomicAdd(&acc[2][l][m], f.z); atomicAdd(&acc[3][l][m], f.w);
    }
  }
  __syncthreads();

  // re-interleave + publish: thread builds float4 from 4 conflict-free scalar
  // LDS reads (bank = mm), stores coalesced 16B
  float* op = ws_pp + (((size_t)b * 4 + seg) * L) * H + chunk * 128;
  for (int e = tid; e < L * 32; e += 256) {   // 512 float4 -> 2 iters
    const int l = e >> 5, mm = e & 31;
    const float4 s = make_float4(acc[0][l][mm], acc[1][l][mm],
                                 acc[2][l][mm], acc[3][l][mm]);
    *(float4*)&op[l * H + mm * 4] = s;
  }
  if (chunk == 0 && tid < L) ws_cntp[(b * 4 + seg) * L + tid] = cnt[tid];
}

// ---------------------------------------------------------------------------
// Kernel 2 (dots+loss): unchanged from round 3 (it was not the bottleneck).
// grid = B*8 octant blocks of 128 threads, 1 token/thread, full H, dot[L] in
// registers, log-softmax + masked mean fused; ping-pong feature prefetch.
#define DOT_BODY(CB, FR)                                                   \
  _Pragma("unroll") for (int q = 0; q < 4; ++q) {                          \
    _Pragma("unroll") for (int l = 0; l < L; ++l) {                        \
      const float4 p = *(const float4*)&pr[l * H + (CB) * 16 + q * 4];     \
      dot[l] += FR[q].x * p.x + FR[q].y * p.y +                            \
                FR[q].z * p.z + FR[q].w * p.w;                             \
    }                                                                      \
  }

__global__ __launch_bounds__(128, 4) void dotsloss_kernel(
    const float* __restrict__ feat, const int* __restrict__ dlen,
    const int* __restrict__ labels, const float* __restrict__ ws_pp,
    const int* __restrict__ ws_cntp, float* __restrict__ out) {
  __shared__ float pr[L * H];   // 16 KB prototypes, full H
  __shared__ int cnts[L];
  __shared__ float red[128];

  const int b = blockIdx.x >> 3;
  const int oct = blockIdx.x & 7;      // 8 x 128-token octants
  const int tid = threadIdx.x;

  const int len = dlen[b];
  if (oct * 128 >= len) return;        // contributes exactly 0 (uniform)
  const int nseg = (len + 255) >> 8;   // 1..4 valid segments

  if (tid < L) {
    const int* cp = ws_cntp + b * 4 * L + tid;
    int c = 0;
    for (int s = 0; s < nseg; ++s) c += cp[s * L];
    cnts[tid] = c;
  }
  __syncthreads();

  // assemble prototypes: sum valid segment partials, divide by count (f4 vec)
  const float4* gp4 = (const float4*)(ws_pp + (size_t)b * 4 * L * H);
  for (int i = tid; i < L * H / 4; i += 128) {   // 1024 float4, 8 iters
    const int l = i >> 6;                        // 64 float4 per label row
    float4 s = gp4[i];                           // nseg >= 1 always
    for (int sg = 1; sg < nseg; ++sg) {
      const float4 t2 = gp4[sg * (L * 64) + i];
      s.x += t2.x; s.y += t2.y; s.z += t2.z; s.w += t2.w;
    }
    const int cn = cnts[l];
    const float inv = (cn > 0) ? 1.f / (float)cn : 0.f;
    ((float4*)pr)[i] = make_float4(s.x * inv, s.y * inv, s.z * inv, s.w * inv);
  }
  __syncthreads();

  const int t = oct * 128 + tid;
  float tok = 0.f;

  if (t < len) {
    const float4* f4 = (const float4*)(feat + ((size_t)b * T + t) * H);
    float dot[L];
#pragma unroll
    for (int l = 0; l < L; ++l) dot[l] = 0.f;

    float4 fa[4], fb[4];
#pragma unroll
    for (int q = 0; q < 4; ++q) fa[q] = f4[q];

    for (int cb = 0; cb < 14; cb += 2) {
#pragma unroll
      for (int q = 0; q < 4; ++q) fb[q] = f4[(cb + 1) * 4 + q];
      DOT_BODY(cb, fa);
#pragma unroll
      for (int q = 0; q < 4; ++q) fa[q] = f4[(cb + 2) * 4 + q];
      DOT_BODY(cb + 1, fb);
    }
#pragma unroll
    for (int q = 0; q < 4; ++q) fb[q] = f4[15 * 4 + q];
    DOT_BODY(14, fa);
    DOT_BODY(15, fb);

    float lg[L];
#pragma unroll
    for (int l = 0; l < L; ++l)
      lg[l] = (cnts[l] > 0) ? dot[l] * INV_TEMP : NEG_INF;
    float m = lg[0];
#pragma unroll
    for (int l = 1; l < L; ++l) m = fmaxf(m, lg[l]);
    float se = 0.f;
#pragma unroll
    for (int l = 0; l < L; ++l) se += expf(lg[l] - m);
    const float lsp = m + logf(se);

    const int lab = labels[(size_t)b * T + t];
    float pos = 0.f;
#pragma unroll
    for (int l = 0; l < L; ++l) pos += (l == lab) ? lg[l] : 0.f;

    tok = lsp - pos;
  }

  red[tid] = tok;
  __syncthreads();
#pragma unroll
  for (int s = 64; s > 0; s >>= 1) {
    if (tid < s) red[tid] += red[tid + s];
    __syncthreads();
  }
  if (tid == 0) atomicAdd(out, red[0] / ((float)len * (float)B));
}

extern "C" void kernel_launch(void* const* d_in, const int* in_sizes, int n_in,
                              void* d_out, int out_size, void* d_ws, size_t ws_size,
                              hipStream_t stream) {
  const float* feat = (const float*)d_in[0];
  const int* dlen = (const int*)d_in[1];
  const int* labels = (const int*)d_in[2];
  float* out = (float*)d_out;

  float* ws_pp = (float*)d_ws;                           // B*4*L*H floats
  int* ws_cntp = (int*)(ws_pp + (size_t)B * 4 * L * H);  // B*4*L ints

  proto_kernel<<<B * 8, 256, 0, stream>>>(feat, dlen, labels, ws_pp,
                                          ws_cntp, out);
  dotsloss_kernel<<<B * 8, 128, 0, stream>>>(feat, dlen, labels, ws_pp,
                                             ws_cntp, out);
}

// Round 5
// 215.895 us; speedup vs baseline: 1.7478x; 1.7478x over previous
//
#include <hip/hip_runtime.h>
#include <math.h>

#define B 128
#define T 1024
#define H 256
#define L 16
#define INV_TEMP (1.0f/0.07f)
#define NEG_INF -1e30f

// ws layout (only seg<nseg regions are ever written/read -> no memset):
//   ws_pp   : float[B][4][L][H]   per-seg prototype partial sums   8 MB
//   ws_cntp : int[B][4][L]        per-seg label counts             32 KB

// ---------------------------------------------------------------------------
// Kernel 1 (v5): GATHER formulation. Counting-sort tokens by label into LDS
// index lists, then each thread owns (label l, float4 column cs) and gathers
// the cnt[l] member rows from global into a register accumulator.
// No LDS feature traffic, no RMW chains, no float atomics (v4's ds_add_f32
// serialized at 173 us; v3's aliasing RMW chains at ~50 us). Only dep chain
// is the 4-cycle FMA on the accumulator; loads batched 8-deep independent.
// grid = B * 4 segs * 4 chunks = 2048 blocks, 256 thr (~4.4 active blk/CU).
__global__ __launch_bounds__(256) void proto_kernel(
    const float* __restrict__ feat, const int* __restrict__ dlen,
    const int* __restrict__ labels, float* __restrict__ ws_pp,
    int* __restrict__ ws_cntp, float* __restrict__ out) {
  __shared__ int idx[L][256];   // 16 KB: token lists per label
  __shared__ int cnt[L];

  const int bx = blockIdx.x;
  if (bx == 0 && threadIdx.x == 0) out[0] = 0.f;   // replaces memset dispatch

  const int b = bx >> 4;
  const int seg = (bx >> 2) & 3;
  const int ch = bx & 3;          // 64-float chunk of H
  const int tid = threadIdx.x;

  const int len = dlen[b];
  if (seg * 256 >= len) return;   // uniform exit, before any barrier
  int segLen = len - seg * 256;
  if (segLen > 256) segLen = 256;

  if (tid < L) cnt[tid] = 0;
  __syncthreads();
  if (tid < segLen) {
    const int l = labels[(size_t)b * T + seg * 256 + tid];
    const int p = atomicAdd(&cnt[l], 1);   // 256 int atomics total: cheap
    idx[l][p] = tid;
  }
  __syncthreads();

  const int l = tid >> 4;         // owned label
  const int cs = tid & 15;        // owned float4 within the 64-float chunk
  // float4 view: token tok's element = fb4[tok * (H/4)]
  const float4* fb4 = (const float4*)feat +
      ((size_t)b * T + seg * 256) * (H / 4) + ch * 16 + cs;

  const int c = cnt[l];
  float4 a = make_float4(0.f, 0.f, 0.f, 0.f);
  int i = 0;
  for (; i + 8 <= c; i += 8) {    // 8 independent loads in flight
    int t8[8];
#pragma unroll
    for (int u = 0; u < 8; ++u) t8[u] = idx[l][i + u];
    float4 f8[8];
#pragma unroll
    for (int u = 0; u < 8; ++u) f8[u] = fb4[(size_t)t8[u] * (H / 4)];
#pragma unroll
    for (int u = 0; u < 8; ++u) {
      a.x += f8[u].x; a.y += f8[u].y; a.z += f8[u].z; a.w += f8[u].w;
    }
  }
  for (; i < c; ++i) {
    const float4 f = fb4[(size_t)idx[l][i] * (H / 4)];
    a.x += f.x; a.y += f.y; a.z += f.z; a.w += f.w;
  }

  // unconditional write: empty labels publish zeros (consumer reads all L)
  *(float4*)(ws_pp + (((size_t)b * 4 + seg) * L + l) * H + ch * 64 + cs * 4) = a;
  if (ch == 0 && tid < L) ws_cntp[(b * 4 + seg) * L + tid] = cnt[tid];
}

// ---------------------------------------------------------------------------
// Kernel 2 (v5): dots+loss with 2-token pr-read sharing. Block = 256-token
// quarter; thread = (token-slot ts, H-half hh) -> 2 tokens x 128 floats.
// pr addresses are wave-uniform (hh constant per wave) -> broadcast reads,
// each serving 2 tokens (halves DS issue vs the 1-token/thread R3 version).
// Halves combined via LDS part[256][L]; softmax + masked mean fused.
__global__ __launch_bounds__(256) void dotsloss_kernel(
    const float* __restrict__ feat, const int* __restrict__ dlen,
    const int* __restrict__ labels, const float* __restrict__ ws_pp,
    const int* __restrict__ ws_cntp, float* __restrict__ out) {
  __shared__ float pr[L * H];      // 16 KB prototypes, full H
  __shared__ float part[256][L];   // 16 KB cross-half partial dots
  __shared__ int cnts[L];
  __shared__ float red[256];

  const int b = blockIdx.x >> 2;
  const int q = blockIdx.x & 3;    // 256-token quarter
  const int tid = threadIdx.x;

  const int len = dlen[b];
  if (q * 256 >= len) return;      // uniform exit
  const int nseg = (len + 255) >> 8;

  if (tid < L) {
    const int* cp = ws_cntp + b * 4 * L + tid;
    int c = 0;
    for (int s = 0; s < nseg; ++s) c += cp[s * L];
    cnts[tid] = c;
  }
  __syncthreads();

  // assemble prototypes: sum valid segment partials, divide by count
  const float4* gp4 = (const float4*)(ws_pp + (size_t)b * 4 * L * H);
  for (int i = tid; i < L * H / 4; i += 256) {   // 1024 float4, 4 iters
    const int l = i >> 6;                        // 64 float4 per label row
    float4 s = gp4[i];                           // nseg >= 1 always
    for (int sg = 1; sg < nseg; ++sg) {
      const float4 t2 = gp4[sg * (L * 64) + i];
      s.x += t2.x; s.y += t2.y; s.z += t2.z; s.w += t2.w;
    }
    const int cn = cnts[l];
    const float inv = (cn > 0) ? 1.f / (float)cn : 0.f;
    ((float4*)pr)[i] = make_float4(s.x * inv, s.y * inv, s.z * inv, s.w * inv);
  }
  __syncthreads();

  const int ts = tid & 127;
  const int hh = tid >> 7;         // H-half; constant within each wave
  const int t0 = q * 256 + ts;
  const int t1 = t0 + 128;         // always < T: loads safe, value masked

  const float4* fA = (const float4*)feat + ((size_t)b * T + t0) * (H / 4) + hh * 32;
  const float4* fB = (const float4*)feat + ((size_t)b * T + t1) * (H / 4) + hh * 32;

  float dot0[L], dot1[L];
#pragma unroll
  for (int l = 0; l < L; ++l) { dot0[l] = 0.f; dot1[l] = 0.f; }

#pragma unroll 2
  for (int cb = 0; cb < 8; ++cb) {   // 16-float chunks of this 128-float half
    float4 fa[4], fb_[4];
#pragma unroll
    for (int q4 = 0; q4 < 4; ++q4) {
      fa[q4] = fA[cb * 4 + q4];
      fb_[q4] = fB[cb * 4 + q4];
    }
#pragma unroll
    for (int q4 = 0; q4 < 4; ++q4) {
#pragma unroll
      for (int l = 0; l < L; ++l) {
        const float4 p = *(const float4*)&pr[l * H + hh * 128 + cb * 16 + q4 * 4];
        dot0[l] += fa[q4].x * p.x + fa[q4].y * p.y +
                   fa[q4].z * p.z + fa[q4].w * p.w;
        dot1[l] += fb_[q4].x * p.x + fb_[q4].y * p.y +
                   fb_[q4].z * p.z + fb_[q4].w * p.w;
      }
    }
  }

  if (hh == 1) {
#pragma unroll
    for (int l = 0; l < L; ++l) {
      part[ts][l] = dot0[l];
      part[ts + 128][l] = dot1[l];
    }
  }
  __syncthreads();

  float tok = 0.f;
  if (hh == 0) {
#pragma unroll
    for (int k = 0; k < 2; ++k) {
      const int t = t0 + k * 128;
      if (t < len) {
        float lg[L];
#pragma unroll
        for (int l = 0; l < L; ++l) {
          const float d = (k == 0 ? dot0[l] : dot1[l]) + part[ts + k * 128][l];
          lg[l] = (cnts[l] > 0) ? d * INV_TEMP : NEG_INF;
        }
        float m = lg[0];
#pragma unroll
        for (int l = 1; l < L; ++l) m = fmaxf(m, lg[l]);
        float se = 0.f;
#pragma unroll
        for (int l = 0; l < L; ++l) se += expf(lg[l] - m);
        const float lsp = m + logf(se);

        const int lab = labels[(size_t)b * T + t];
        float pos = 0.f;
#pragma unroll
        for (int l = 0; l < L; ++l) pos += (l == lab) ? lg[l] : 0.f;

        tok += lsp - pos;
      }
    }
  }

  red[tid] = tok;
  __syncthreads();
#pragma unroll
  for (int s = 128; s > 0; s >>= 1) {
    if (tid < s) red[tid] += red[tid + s];
    __syncthreads();
  }
  if (tid == 0) atomicAdd(out, red[0] / ((float)len * (float)B));
}

extern "C" void kernel_launch(void* const* d_in, const int* in_sizes, int n_in,
                              void* d_out, int out_size, void* d_ws, size_t ws_size,
                              hipStream_t stream) {
  const float* feat = (const float*)d_in[0];
  const int* dlen = (const int*)d_in[1];
  const int* labels = (const int*)d_in[2];
  float* out = (float*)d_out;

  float* ws_pp = (float*)d_ws;                           // B*4*L*H floats
  int* ws_cntp = (int*)(ws_pp + (size_t)B * 4 * L * H);  // B*4*L ints

  proto_kernel<<<B * 16, 256, 0, stream>>>(feat, dlen, labels, ws_pp,
                                           ws_cntp, out);
  dotsloss_kernel<<<B * 4, 256, 0, stream>>>(feat, dlen, labels, ws_pp,
                                             ws_cntp, out);
}